// Round 5
// baseline (775.414 us; speedup 1.0000x reference)
//
#include <hip/hip_runtime.h>
#include <hip/hip_bf16.h>
#include <hip/hip_cooperative_groups.h>

namespace cg = cooperative_groups;

#define DEPTH   8
#define NNODES  87381   // (4^9-1)/3
#define KIN     640     // E + A*H
#define NOUTS   896     // 3H + A*H
// fragment-major Wc: [ct=0..55][kt=0..19][lane=0..63][j=0..7]
//   element (out=ct*16+(lane&15), k=kt*32+(lane>>4)*8+j)
#define CT_STRIDE 10240   // 20*64*8
#define KT_STRIDE 512     // 64*8

typedef __attribute__((ext_vector_type(8))) unsigned short ushort8;
typedef __attribute__((ext_vector_type(4))) unsigned short ushort4v;
typedef __attribute__((ext_vector_type(8))) __bf16        bf16x8;
typedef __attribute__((ext_vector_type(4))) float         f32x4;

union Frag8 { ushort8 u; bf16x8 b; };

__device__ __forceinline__ unsigned short f2bf(float f) {
    unsigned int x = __float_as_uint(f);
    x += 0x7fffu + ((x >> 16) & 1u);          // round-to-nearest-even
    return (unsigned short)(x >> 16);
}
__device__ __forceinline__ float sigf(float x) {
    return __builtin_amdgcn_rcpf(1.0f + __expf(-x));
}
__device__ __forceinline__ float tanh_fast(float x) { return 2.0f * sigf(2.0f * x) - 1.0f; }

// ---------------- weight packing (fragment-major) ----------------
__global__ __launch_bounds__(256) void build_wc(
    const float* __restrict__ W_iou, const float* __restrict__ U_iou,
    const float* __restrict__ W_f,   const float* __restrict__ U_f,
    unsigned short* __restrict__ Wc)
{
    int idx = blockIdx.x * 256 + threadIdx.x;     // 0 .. 896*640-1
    int ct  = idx / CT_STRIDE;
    int r1  = idx - ct * CT_STRIDE;
    int kt  = r1 >> 9;
    int r2  = r1 & 511;
    int ln  = r2 >> 3;
    int j   = r2 & 7;
    int out = ct * 16 + (ln & 15);
    int k   = kt * 32 + ((ln >> 4) << 3) + j;
    float v;
    if (out < 384) {
        v = (k < 128) ? W_iou[out * 128 + k] : U_iou[(size_t)out * 512 + (k - 128)];
    } else {
        int o2 = out - 384;
        v = (k < 128) ? W_f[(o2 & 127) * 128 + k] : U_f[(size_t)o2 * 512 + (k - 128)];
    }
    Wc[idx] = f2bf(v);
}

// biasc[o] = combined bias; hUc[o] = biasc[o] + (Uc . h0cat)[o]  (leaf constant)
__global__ __launch_bounds__(64) void build_consts(
    const float* __restrict__ U_iou, const float* __restrict__ U_f,
    const float* __restrict__ b_iou, const float* __restrict__ b_uiou,
    const float* __restrict__ b_wf,  const float* __restrict__ b_uf,
    const float* __restrict__ h0,
    float* __restrict__ biasc, float* __restrict__ hUc)
{
    int o = blockIdx.x * 64 + threadIdx.x;
    if (o >= NOUTS) return;
    float b = (o < 384) ? (b_iou[o] + b_uiou[o])
                        : (b_wf[(o - 384) & 127] + b_uf[o - 384]);
    const float* Urow = (o < 384) ? (U_iou + (size_t)o * 512)
                                  : (U_f + (size_t)(o - 384) * 512);
    float s0 = 0.f, s1 = 0.f;
    #pragma unroll 4
    for (int k = 0; k < 512; k += 8) {
        float4 u0 = *(const float4*)(Urow + k);
        float4 hv0 = *(const float4*)(h0 + k);
        float4 u1 = *(const float4*)(Urow + k + 4);
        float4 hv1 = *(const float4*)(h0 + k + 4);
        s0 += u0.x*hv0.x + u0.y*hv0.y + u0.z*hv0.z + u0.w*hv0.w;
        s1 += u1.x*hv1.x + u1.y*hv1.y + u1.z*hv1.z + u1.w*hv1.w;
    }
    biasc[o] = b;
    hUc[o]   = b + s0 + s1;
}

// ---------------- leaf kernel (level 8): BM=64, K=128, full-N per block -----
__global__ __launch_bounds__(512) void tree_leaf(
    const float* __restrict__ emb, const unsigned short* __restrict__ Wc,
    const float* __restrict__ hUc, const float* __restrict__ c0,
    float* __restrict__ outh, float* __restrict__ outc,
    unsigned short* __restrict__ hb, int n)
{
    __shared__ __align__(16) char lds[2 * 8192];
    const int tid   = threadIdx.x;
    const int node0 = blockIdx.x * 64;
    const int srow  = tid >> 3;
    const int skq   = (tid & 7) << 3;
    const unsigned swz = (unsigned)((srow * 128 + skq * 2) ^ ((srow & 7) << 4));
    int r = node0 + srow; if (r >= n) r = n - 1;

    const int wv = tid >> 6, ln = tid & 63, grp = ln >> 4, cl = ln & 15;

    f32x4 acc[4][7] = {};
    float4 pv0, pv1;
    auto issue = [&](int ks) {
        const float* src = emb + (size_t)r * 128 + ks * 64 + skq;
        pv0 = *(const float4*)src;
        pv1 = *(const float4*)(src + 4);
    };
    auto pack_write = [&](char* buf) {
        ushort8 w;
        w[0] = f2bf(pv0.x); w[1] = f2bf(pv0.y); w[2] = f2bf(pv0.z); w[3] = f2bf(pv0.w);
        w[4] = f2bf(pv1.x); w[5] = f2bf(pv1.y); w[6] = f2bf(pv1.z); w[7] = f2bf(pv1.w);
        *(ushort8*)(buf + swz) = w;
    };

    const unsigned short* wp[7];
    #pragma unroll
    for (int cf = 0; cf < 7; ++cf)
        wp[cf] = Wc + (size_t)(cf * 8 + wv) * CT_STRIDE + (size_t)ln * 8;

    issue(0);
    pack_write(lds);
    #pragma unroll
    for (int ks = 0; ks < 2; ++ks) {
        char* cur = lds + (size_t)(ks & 1) * 8192;
        if (ks == 0) issue(1);
        __syncthreads();
        #pragma unroll
        for (int kc = 0; kc < 2; ++kc) {
            const int kt = ks * 2 + kc;
            Frag8 bfr[7];
            #pragma unroll
            for (int cf = 0; cf < 7; ++cf)
                bfr[cf].u = *(const ushort8*)(wp[cf] + kt * KT_STRIDE);
            #pragma unroll
            for (int rf = 0; rf < 4; ++rf) {
                const int row = rf * 16 + cl;
                const unsigned rby = (unsigned)(row * 128 + kc * 64 + grp * 16) ^ ((row & 7) << 4);
                Frag8 afr; afr.u = *(const ushort8*)(cur + rby);
                #pragma unroll
                for (int cf = 0; cf < 7; ++cf)
                    acc[rf][cf] = __builtin_amdgcn_mfma_f32_16x16x32_bf16(
                        afr.b, bfr[cf].b, acc[rf][cf], 0, 0, 0);
            }
        }
        if (ks == 0) pack_write(lds + 8192);
    }

    // epilogue: leaf cell (h-part constant hUc, c-in = c0)
    const int d = wv * 16 + cl;
    const float bi = hUc[d];
    const float bo = hUc[128 + d];
    const float bu = hUc[256 + d];
    float bfa[4], cin_leaf[4];
    #pragma unroll
    for (int a = 0; a < 4; ++a) { bfa[a] = hUc[384 + a * 128 + d]; cin_leaf[a] = c0[a * 128 + d]; }

    #pragma unroll
    for (int rf = 0; rf < 4; ++rf) {
        #pragma unroll
        for (int reg = 0; reg < 4; ++reg) {
            const int m = node0 + rf * 16 + grp * 4 + reg;
            if (m < n) {
                const float i_ = acc[rf][0][reg] + bi;
                const float o_ = acc[rf][1][reg] + bo;
                const float u_ = acc[rf][2][reg] + bu;
                float c_ = sigf(i_) * tanh_fast(u_);
                #pragma unroll
                for (int a = 0; a < 4; ++a)
                    c_ += sigf(acc[rf][3 + a][reg] + bfa[a]) * cin_leaf[a];
                const float h_ = sigf(o_) * tanh_fast(c_);
                const size_t oidx = (size_t)m * 128 + d;
                outh[oidx] = h_;
                outc[oidx] = c_;
                hb[oidx]   = f2bf(h_);
            }
        }
    }
}

// ---------------- dsplit unit (non-leaf): 32 rows x one 16-col d-group ------
__device__ __forceinline__ void dsplit_unit(
    const float* __restrict__ emb, const unsigned short* __restrict__ Wc,
    const float* __restrict__ biasc,
    float* __restrict__ outh, float* __restrict__ outc,
    unsigned short* __restrict__ hb,
    char* lds, int n, int off, int cb, int mt, int dg)
{
    const int tid   = threadIdx.x;
    const int node0 = mt * 32;

    // stage A-panel [32 rows][640 k] bf16: x from emb (f32+cvt), h from hb (copy)
    {
        const int srow = tid >> 4;              // 0..31
        const int sc4  = (tid & 15) << 2;       // 0..60 step 4
        int r = node0 + srow; if (r >= n) r = n - 1;
        const unsigned wby = (unsigned)((srow * 128 + sc4 * 2) ^ ((srow & 7) << 4));
        ushort4v w[10];
        const float4 v0 = *(const float4*)(emb + (size_t)(off + r) * 128 + sc4);
        const float4 v1 = *(const float4*)(emb + (size_t)(off + r) * 128 + 64 + sc4);
        #pragma unroll
        for (int i = 2; i < 10; ++i)
            w[i] = *(const ushort4v*)(hb + (size_t)(cb + 4 * r + ((i - 2) >> 1)) * 128
                                         + ((i - 2) & 1) * 64 + sc4);
        w[0][0] = f2bf(v0.x); w[0][1] = f2bf(v0.y); w[0][2] = f2bf(v0.z); w[0][3] = f2bf(v0.w);
        w[1][0] = f2bf(v1.x); w[1][1] = f2bf(v1.y); w[1][2] = f2bf(v1.z); w[1][3] = f2bf(v1.w);
        #pragma unroll
        for (int i = 0; i < 10; ++i)
            *(ushort4v*)(lds + i * 4096 + wby) = w[i];
    }
    __syncthreads();

    // barrier-free K-loop: wave = (rf, kq), 5 kt each
    const int wv  = tid >> 6;
    const int ln  = tid & 63;
    const int grp = ln >> 4;
    const int cl  = ln & 15;
    const int rf  = wv & 1;
    const int kq  = wv >> 1;
    const int row = rf * 16 + cl;
    const int swr = (row & 7) << 4;

    const unsigned short* wp[7];
    #pragma unroll
    for (int cf = 0; cf < 7; ++cf)
        wp[cf] = Wc + (size_t)(cf * 8 + dg) * CT_STRIDE + (size_t)ln * 8;

    f32x4 acc[7] = {};
    #pragma unroll
    for (int t = 0; t < 5; ++t) {
        const int kt = kq * 5 + t;
        Frag8 afr;
        afr.u = *(const ushort8*)(lds + (kt >> 1) * 4096 + row * 128
                                  + (((kt & 1) * 64 + grp * 16) ^ swr));
        Frag8 bfr[7];
        #pragma unroll
        for (int cf = 0; cf < 7; ++cf)
            bfr[cf].u = *(const ushort8*)(wp[cf] + (size_t)kt * KT_STRIDE);
        #pragma unroll
        for (int cf = 0; cf < 7; ++cf)
            acc[cf] = __builtin_amdgcn_mfma_f32_16x16x32_bf16(
                afr.b, bfr[cf].b, acc[cf], 0, 0, 0);
    }
    __syncthreads();                            // panel dead; LDS reused

    // cross-wave K reduction
    float* red = (float*)lds;
    const int slot = ((kq * 2 + rf) * 64 + ln) * 28;
    if (kq != 0) {
        #pragma unroll
        for (int cf = 0; cf < 7; ++cf)
            *(f32x4*)(red + slot + cf * 4) = acc[cf];
    }
    __syncthreads();
    if (kq == 0) {
        #pragma unroll
        for (int q = 1; q < 4; ++q) {
            const int s2 = ((q * 2 + rf) * 64 + ln) * 28;
            #pragma unroll
            for (int cf = 0; cf < 7; ++cf)
                acc[cf] += *(const f32x4*)(red + s2 + cf * 4);
        }
        const int d = dg * 16 + cl;
        const float bi = biasc[d];
        const float bo = biasc[128 + d];
        const float bu = biasc[256 + d];
        float bfa[4];
        #pragma unroll
        for (int a = 0; a < 4; ++a) bfa[a] = biasc[384 + a * 128 + d];

        #pragma unroll
        for (int reg = 0; reg < 4; ++reg) {
            const int m = node0 + rf * 16 + grp * 4 + reg;
            if (m < n) {
                const float i_ = acc[0][reg] + bi;
                const float o_ = acc[1][reg] + bo;
                const float u_ = acc[2][reg] + bu;
                float c_ = sigf(i_) * tanh_fast(u_);
                #pragma unroll
                for (int a = 0; a < 4; ++a)
                    c_ += sigf(acc[3 + a][reg] + bfa[a]) * outc[(size_t)(cb + 4 * m + a) * 128 + d];
                const float h_ = sigf(o_) * tanh_fast(c_);
                const size_t oidx = (size_t)(off + m) * 128 + d;
                outh[oidx] = h_;
                outc[oidx] = c_;
                hb[oidx]   = f2bf(h_);
            }
        }
    }
}

__global__ __launch_bounds__(512) void tree_dsplit(
    const float* __restrict__ emb, const unsigned short* __restrict__ Wc,
    const float* __restrict__ biasc,
    float* __restrict__ outh, float* __restrict__ outc,
    unsigned short* __restrict__ hb,
    int n, int off, int cb)
{
    __shared__ __align__(16) char lds[57344];
    dsplit_unit(emb, Wc, biasc, outh, outc, hb, lds, n, off, cb,
                blockIdx.x >> 3, blockIdx.x & 7);
}

// levels 6..0 in one cooperative launch (256 blocks), grid.sync between levels
__global__ __launch_bounds__(512) void tree_coop(
    const float* __restrict__ emb, const unsigned short* __restrict__ Wc,
    const float* __restrict__ biasc,
    float* __restrict__ outh, float* __restrict__ outc,
    unsigned short* __restrict__ hb)
{
    __shared__ __align__(16) char lds[57344];
    const int ns[7]   = {4096, 1024, 256, 64, 16, 4, 1};
    const int offs[7] = {81920, 86016, 87040, 87296, 87360, 87376, 87380};
    const int cbs[7]  = {65536, 81920, 86016, 87040, 87296, 87360, 87376};
    cg::grid_group grid = cg::this_grid();
    #pragma unroll 1
    for (int li = 0; li < 7; ++li) {
        const int n = ns[li], off = offs[li], cb = cbs[li];
        const int units = ((n + 31) >> 5) * 8;
        for (int u = blockIdx.x; u < units; u += gridDim.x) {
            dsplit_unit(emb, Wc, biasc, outh, outc, hb, lds, n, off, cb,
                        u >> 3, u & 7);
            __syncthreads();
        }
        __threadfence();
        grid.sync();
    }
}

extern "C" void kernel_launch(void* const* d_in, const int* in_sizes, int n_in,
                              void* d_out, int out_size, void* d_ws, size_t ws_size,
                              hipStream_t stream)
{
    const float* emb    = (const float*)d_in[0];
    const float* W_iou  = (const float*)d_in[1];
    const float* b_iou  = (const float*)d_in[2];
    const float* U_iou  = (const float*)d_in[3];
    const float* b_uiou = (const float*)d_in[4];
    const float* W_f    = (const float*)d_in[5];
    const float* b_wf   = (const float*)d_in[6];
    const float* U_f    = (const float*)d_in[7];
    const float* b_uf   = (const float*)d_in[8];
    const float* h0     = (const float*)d_in[9];
    const float* c0     = (const float*)d_in[10];

    unsigned short* Wc = (unsigned short*)d_ws;                   // 1,146,880 B
    float* biasc = (float*)((char*)d_ws + (size_t)NOUTS * KIN * 2);
    float* hUc   = biasc + NOUTS;
    unsigned short* hb = (unsigned short*)((char*)d_ws + (size_t)NOUTS * KIN * 2
                                           + 2 * NOUTS * sizeof(float));  // 22.4 MB

    hipLaunchKernelGGL(build_wc, dim3((NOUTS * KIN) / 256), dim3(256), 0, stream,
                       W_iou, U_iou, W_f, U_f, Wc);
    hipLaunchKernelGGL(build_consts, dim3((NOUTS + 63) / 64), dim3(64), 0, stream,
                       U_iou, U_f, b_iou, b_uiou, b_wf, b_uf, h0, biasc, hUc);

    float* outh = (float*)d_out;
    float* outc = outh + (size_t)NNODES * 128;

    // level 8 (leaf): off=0, n=65536
    hipLaunchKernelGGL(tree_leaf, dim3(1024), dim3(512), 0, stream,
                       emb, Wc, hUc, c0, outh, outc, hb, 65536);
    // level 7: n=16384, off=65536, cb=0
    hipLaunchKernelGGL(tree_dsplit, dim3(4096), dim3(512), 0, stream,
                       emb, Wc, biasc, outh, outc, hb, 16384, 65536, 0);

    // levels 6..0: cooperative single launch, fallback to per-level launches
    const float* a_emb = emb; const unsigned short* a_wc = Wc;
    const float* a_biasc = biasc; float* a_outh = outh; float* a_outc = outc;
    unsigned short* a_hb = hb;
    void* cargs[] = {(void*)&a_emb, (void*)&a_wc, (void*)&a_biasc,
                     (void*)&a_outh, (void*)&a_outc, (void*)&a_hb};
    hipError_t ce = hipLaunchCooperativeKernel((const void*)tree_coop,
                                               dim3(256), dim3(512), cargs, 0, stream);
    if (ce != hipSuccess) {
        (void)hipGetLastError();   // clear error state
        const int ns[7]   = {4096, 1024, 256, 64, 16, 4, 1};
        const int offs[7] = {81920, 86016, 87040, 87296, 87360, 87376, 87380};
        const int cbs[7]  = {65536, 81920, 86016, 87040, 87296, 87360, 87376};
        for (int li = 0; li < 7; ++li) {
            const int nb = ((ns[li] + 31) / 32) * 8;
            hipLaunchKernelGGL(tree_dsplit, dim3(nb), dim3(512), 0, stream,
                               emb, Wc, biasc, outh, outc, hb,
                               ns[li], offs[li], cbs[li]);
        }
    }
}